// Round 8
// baseline (224.263 us; speedup 1.0000x reference)
//
#include <hip/hip_runtime.h>
#include <hip/hip_bf16.h>

typedef __attribute__((ext_vector_type(8))) short bf16x8;
typedef __attribute__((ext_vector_type(4))) float f32x4;
using bf16 = __hip_bfloat16;

#define NTOK 4096
#define EPS_LN 1e-5f
#define QSCL 0.1803368801111244f  // 0.125 * log2(e): softmax in exp2 domain

enum { EPI_F32 = 0, EPI_QKV = 1, EPI_RELU_BF16 = 2 };

__device__ inline void gload_lds16(const void* g, void* l) {
  __builtin_amdgcn_global_load_lds(
      (const __attribute__((address_space(1))) char*)g,
      (__attribute__((address_space(3))) char*)l, 16, 0, 0);
}

__device__ inline unsigned ldsoff(const void* p) {
  return (unsigned)(size_t)(const __attribute__((address_space(3))) char*)p;
}

__device__ inline unsigned short f2bfu(float x) {
  bf16 h = __float2bfloat16(x);
  return __builtin_bit_cast(unsigned short, h);
}
__device__ inline bf16 to_bf16(float v) { return __float2bfloat16(v); }
__device__ inline bf16 to_bf16(bf16 v) { return v; }

// ---------------- prep kernels ----------------

__global__ __launch_bounds__(256) void cvt_bf16_kernel(const float* __restrict__ src,
                                                       bf16* __restrict__ dst, int n4) {
  int i = blockIdx.x * 256 + threadIdx.x;
  if (i >= n4) return;
  float4 v = ((const float4*)src)[i];
  ushort4 o;
  o.x = f2bfu(v.x); o.y = f2bfu(v.y); o.z = f2bfu(v.z); o.w = f2bfu(v.w);
  ((ushort4*)dst)[i] = o;
}

template <typename ST>
__global__ __launch_bounds__(256) void transpose_cvt(const ST* __restrict__ src,
                                                     bf16* __restrict__ dst, int R, int C) {
  __shared__ bf16 tile[32][33];
  int o = blockIdx.z;
  int r0 = blockIdx.y * 32, c0 = blockIdx.x * 32;
  int tx = threadIdx.x & 31, ty = threadIdx.x >> 5;
  const ST* s = src + (size_t)o * R * C;
  bf16* d = dst + (size_t)o * R * C;
#pragma unroll
  for (int i = 0; i < 32; i += 8)
    tile[ty + i][tx] = to_bf16(s[(size_t)(r0 + ty + i) * C + (c0 + tx)]);
  __syncthreads();
#pragma unroll
  for (int i = 0; i < 32; i += 8)
    d[(size_t)(c0 + ty + i) * R + (r0 + tx)] = tile[tx][ty + i];
}

__global__ __launch_bounds__(256) void pack_bias_kernel(const float* __restrict__ bq,
                                                        const float* __restrict__ bk,
                                                        const float* __restrict__ bv,
                                                        float* __restrict__ out) {
  int i = blockIdx.x * 256 + threadIdx.x;
  if (i >= 3072) return;
  out[i] = (i < 1024) ? bq[i] : (i < 2048 ? bk[i - 1024] : bv[i - 2048]);
}

// ---------------- GEMM: 256x256 tile, BK=32 x 4-buffer deep pipeline ----------
// C[M,N] = A[M,K] x Bt[N,K]^T ; optional split-K partials. 512 thr = 8 waves
// (2m x 4n), per-wave output 128x64. 32-deep K-subtiles; stage subtile s+3
// while computing s; vmcnt(8) per phase => 3-phase (~1200cy) load cover.

#define VM8 asm volatile("s_waitcnt vmcnt(8)" ::: "memory")
#define VM4 asm volatile("s_waitcnt vmcnt(4)" ::: "memory")
#define VM0 asm volatile("s_waitcnt vmcnt(0)" ::: "memory")
#define LGKM0 asm volatile("s_waitcnt lgkmcnt(0)" ::: "memory")
#define SCHED0 __builtin_amdgcn_sched_barrier(0)
#define NOVM

// 12 balanced ds_reads; buffer selected by literal byte offset (0/16384/...)
#define LD32(OFFLIT) { \
  _Pragma("unroll") for (int i = 0; i < 8; ++i) \
    asm volatile("ds_read_b128 %0, %1 offset:" #OFFLIT : "=v"(a[i]) : "v"(adA[i])); \
  _Pragma("unroll") for (int j = 0; j < 4; ++j) \
    asm volatile("ds_read_b128 %0, %1 offset:" #OFFLIT : "=v"(b[j]) : "v"(adB[j])); }

// stage one 32KB subtile: 2 A-loads + 2 B-loads per thread
#define SA32(OFF, DD) { _Pragma("unroll") for (int q = 0; q < 2; ++q) \
    gload_lds16(gA0 + (OFF) + (size_t)(q * 128) * lda2, \
                sAbase + (DD) * 16384 + q * 8192 + w * 1024); }
#define SB32(OFF, DD) { _Pragma("unroll") for (int q = 0; q < 2; ++q) \
    gload_lds16(gB0 + (OFF) + (size_t)(q * 128) * ldb2, \
                sBbase + (DD) * 16384 + q * 8192 + w * 1024); }

#define MM32 { _Pragma("unroll") for (int i = 0; i < 8; ++i) \
  _Pragma("unroll") for (int j = 0; j < 4; ++j) \
    acc[i][j] = __builtin_amdgcn_mfma_f32_16x16x32_bf16(a[i], b[j], acc[i][j], 0, 0, 0); }

#define PH32(OFFLIT, STG, VMS) { \
  LD32(OFFLIT); \
  STG; \
  __builtin_amdgcn_s_barrier(); \
  LGKM0; SCHED0; \
  __builtin_amdgcn_s_setprio(1); \
  MM32; \
  __builtin_amdgcn_s_setprio(0); \
  VMS; \
  __builtin_amdgcn_s_barrier(); }

__global__ __launch_bounds__(512, 2) void gemm256(
    const bf16* __restrict__ A, int lda,
    const bf16* __restrict__ Bt, int ldb,
    int M, int N, int K,  // K = per-split extent; K % 128 == 0
    int nbm, int nbn, int nsplit,
    const float* __restrict__ bias,
    float* __restrict__ Cf, bf16* __restrict__ Cb,
    bf16* __restrict__ Qd, bf16* __restrict__ Kd, bf16* __restrict__ Vd,
    int mode) {
  __shared__ bf16 sA[4][256][32];
  __shared__ bf16 sB[4][256][32];
  const int nwg = nbm * nbn * nsplit;
  const int orig = blockIdx.x;
  const int wgid = (orig % 8) * (nwg / 8) + orig / 8;  // nwg % 8 == 0
  const int sp = wgid / (nbm * nbn);
  const int rem = wgid % (nbm * nbn);
  const int bm = rem / nbn, bn = rem % nbn;
  const int tid = threadIdx.x;
  const int w = tid >> 6, lane = tid & 63;
  const int wm = w >> 2, wn = w & 3;
  const int ri = lane & 15, kg = lane >> 4;
  const bf16* Ab = A + (size_t)bm * 256 * lda + (size_t)sp * K;
  const bf16* Bb = Bt + (size_t)bn * 256 * ldb + (size_t)sp * K;
  const int NS = K / 32;  // subtiles; NS % 4 == 0, NS >= 8
  const size_t lda2 = (size_t)lda * 2, ldb2 = (size_t)ldb * 2;
  char* sAbase = (char*)&sA[0][0][0];
  char* sBbase = (char*)&sB[0][0][0];

  // loop-invariant LDS read addresses ([256][32] rows of 64B, swz=(row&3)<<4)
  unsigned adA[8], adB[4];
  const unsigned sA0 = ldsoff(sAbase), sB0 = ldsoff(sBbase);
#pragma unroll
  for (int i = 0; i < 8; ++i) {
    int row = wm * 128 + i * 16 + ri;
    adA[i] = sA0 + row * 64 + ((kg * 16) ^ ((row & 3) << 4));
  }
#pragma unroll
  for (int j = 0; j < 4; ++j) {
    int row = wn * 64 + j * 16 + ri;
    adB[j] = sB0 + row * 64 + ((kg * 16) ^ ((row & 3) << 4));
  }

  // per-lane stage base pointers (row = w*16 + lane>>2, pre-swizzled col)
  const int r4 = lane >> 2, c4 = lane & 3;
  const int scb = (c4 * 16) ^ ((r4 & 3) << 4);
  const char* gA0 = (const char*)Ab + (size_t)(w * 16 + r4) * lda2 + scb;
  const char* gB0 = (const char*)Bb + (size_t)(w * 16 + r4) * ldb2 + scb;

  f32x4 acc[8][4] = {};
  bf16x8 a[8], b[4];

  // prologue: subtiles 0,1,2 into buffers 0,1,2
  SA32(0, 0) SB32(0, 0) SA32(64, 1) SB32(64, 1) SA32(128, 2) SB32(128, 2)
  VM8;  // subtile 0 landed
  __builtin_amdgcn_s_barrier();

  const int ngrp = NS / 4 - 1;
  for (int g = 0; g < ngrp; ++g) {
    PH32(0,     SA32(192, 3) SB32(192, 3), VM8)
    PH32(16384, SA32(256, 0) SB32(256, 0), VM8)
    PH32(32768, SA32(320, 1) SB32(320, 1), VM8)
    PH32(49152, SA32(384, 2) SB32(384, 2), VM8)
    gA0 += 256; gB0 += 256;
  }
  // tail group: subtiles NS-4..NS-1; only NS-1 still needs staging
  PH32(0,     SA32(192, 3) SB32(192, 3), VM8)
  PH32(16384, ,                          VM4)
  PH32(32768, ,                          VM0)
  PH32(49152, ,                          NOVM)

  // epilogue: line-contiguous writes (nf innermost)
  const int colbase = bn * 256 + wn * 64 + ri;
  float bv4[4];
#pragma unroll
  for (int nf = 0; nf < 4; ++nf)
    bv4[nf] = (bias && sp == 0) ? bias[colbase + nf * 16] : 0.f;

  if (mode == EPI_QKV) {
    int col0 = bn * 256 + wn * 64;  // which/hh are wave-uniform (256 | 1024 grid)
    int which = col0 >> 10, hh = (col0 >> 6) & 15;
    bf16* dst = (which == 0) ? Qd : (which == 1) ? Kd : Vd;
    float scl = (which == 0) ? QSCL : 1.0f;  // fold softmax scale+log2e into Q
#pragma unroll
    for (int mf = 0; mf < 8; ++mf)
#pragma unroll
      for (int r = 0; r < 4; ++r) {
        int row = bm * 256 + wm * 128 + mf * 16 + kg * 4 + r;
        int bb2 = row >> 10, s = row & 1023;
        bf16* o = dst + (((size_t)(bb2 * 16 + hh)) * 1024 + s) * 64;
#pragma unroll
        for (int nf = 0; nf < 4; ++nf)
          o[nf * 16 + ri] = __float2bfloat16((acc[mf][nf][r] + bv4[nf]) * scl);
      }
  } else if (mode == EPI_F32) {
#pragma unroll
    for (int mf = 0; mf < 8; ++mf)
#pragma unroll
      for (int r = 0; r < 4; ++r) {
        int row = bm * 256 + wm * 128 + mf * 16 + kg * 4 + r;
        float* o = Cf + (size_t)sp * M * N + (size_t)row * N + colbase;
#pragma unroll
        for (int nf = 0; nf < 4; ++nf) o[nf * 16] = acc[mf][nf][r] + bv4[nf];
      }
  } else {  // EPI_RELU_BF16
#pragma unroll
    for (int mf = 0; mf < 8; ++mf)
#pragma unroll
      for (int r = 0; r < 4; ++r) {
        int row = bm * 256 + wm * 128 + mf * 16 + kg * 4 + r;
        bf16* o = Cb + (size_t)row * N + colbase;
#pragma unroll
        for (int nf = 0; nf < 4; ++nf) {
          float v = acc[mf][nf][r] + bv4[nf];
          o[nf * 16] = __float2bfloat16(v > 0.f ? v : 0.f);
        }
      }
  }
}

// ---------------- flash attention: swapped-QK, lane-local softmax ----------------
// grid 1024 = 64 bh * 16 q-tiles (XCD-grouped). 4 waves x 16 q-rows; 4 blk/CU.
__global__ __launch_bounds__(256, 4) void attn_kernel(
    const bf16* __restrict__ Qb, const bf16* __restrict__ Kb,
    const bf16* __restrict__ Vs, bf16* __restrict__ Ob) {
  __shared__ bf16 KV[2][2][64][64];  // [dbuf][0=K rows=key | 1=V^T rows=d]
  __shared__ bf16 Ps[4][16][64];     // per-wave P [query][key], swizzled
  const int orig = blockIdx.x;
  const int blk = (orig & 7) * 128 + (orig >> 3);  // 1024 % 8 == 0
  const int bh = blk >> 4, qt = blk & 15;
  const int bb = bh >> 4, hh = bh & 15;
  const int tid = threadIdx.x, w = tid >> 6, lane = tid & 63;
  const int ri = lane & 15, kg = lane >> 4, r8 = lane >> 3;
  const int cb = ((lane & 7) * 16) ^ ((r8 & 7) << 4);  // pre-swizzled source
  const unsigned rsw = (unsigned)((ri & 7) << 4);
  const bf16* qp = Qb + (size_t)bh * 65536;
  const bf16* kp = Kb + (size_t)bh * 65536;
  const bf16* vp = Vs + (size_t)bh * 65536;
  const int q0 = qt * 64 + w * 16;
  const int c0 = w * 2, c1 = c0 + 1;

  unsigned offk0 = (unsigned)((kg * 16) ^ (int)rsw);
  unsigned offk1 = (unsigned)((64 + kg * 16) ^ (int)rsw);
  unsigned adF[4][2];
  const unsigned kv0 = ldsoff(&KV[0][0][0][0]);
#pragma unroll
  for (int n = 0; n < 4; ++n) {
    unsigned row = (unsigned)((n * 16 + ri) * 128);
    adF[n][0] = kv0 + row + offk0;
    adF[n][1] = kv0 + row + offk1;
  }
  const unsigned ps0 = ldsoff(&Ps[0][0][0]) + (unsigned)(w * 2048 + ri * 128);
  unsigned adPr[2] = {ps0 + offk0, ps0 + offk1};
  char* pwb = (char*)&Ps[0][0][0] + w * 2048 + ri * 128;

  bf16x8 qf[2];
  qf[0] = *(const bf16x8*)(qp + (size_t)(q0 + ri) * 64 + kg * 8);
  qf[1] = *(const bf16x8*)(qp + (size_t)(q0 + ri) * 64 + 32 + kg * 8);

  f32x4 oacc[4] = {};
  float mrun = -1e30f, lrun = 0.f;

#define DSRO(dst, ad, off) \
  asm volatile("ds_read_b128 %0, %1 offset:" #off : "=v"(dst) : "v"(ad))
#define ASTAGE(T, D) { \
    gload_lds16((const char*)(kp + (size_t)((T) * 64 + c0 * 8 + r8) * 64) + cb, \
                (char*)KV + (D) * 16384 + c0 * 1024); \
    gload_lds16((const char*)(kp + (size_t)((T) * 64 + c1 * 8 + r8) * 64) + cb, \
                (char*)KV + (D) * 16384 + c1 * 1024); \
    gload_lds16((const char*)(vp + (size_t)(c0 * 8 + r8) * 1024 + (T) * 64) + cb, \
                (char*)KV + (D) * 16384 + 8192 + c0 * 1024); \
    gload_lds16((const char*)(vp + (size_t)(c1 * 8 + r8) * 1024 + (T) * 64) + cb, \
                (char*)KV + (D) * 16384 + 8192 + c1 * 1024); }

  ASTAGE(0, 0);
  VM0;
  __syncthreads();

  for (int t = 0; t < 16; ++t) {
    const int cur = t & 1;
    if (t < 15) ASTAGE(t + 1, cur ^ 1);  // flies across the whole tile
    const unsigned bo = (unsigned)(cur * 16384);

    bf16x8 kf[2][4];
#pragma unroll
    for (int n = 0; n < 4; ++n) {
      DSRO(kf[0][n], adF[n][0] + bo, 0);
      DSRO(kf[1][n], adF[n][1] + bo, 0);
    }
    LGKM0; SCHED0;
    f32x4 sac[4] = {};
#pragma unroll
    for (int n = 0; n < 4; ++n) {
      sac[n] = __builtin_amdgcn_mfma_f32_16x16x32_bf16(kf[0][n], qf[0], sac[n], 0, 0, 0);
      sac[n] = __builtin_amdgcn_mfma_f32_16x16x32_bf16(kf[1][n], qf[1], sac[n], 0, 0, 0);
    }

    float mx[4];
#pragma unroll
    for (int n = 0; n < 4; ++n)
      mx[n] = fmaxf(fmaxf(sac[n][0], sac[n][1]), fmaxf(sac[n][2], sac[n][3]));
    float mt = fmaxf(fmaxf(mx[0], mx[1]), fmaxf(mx[2], mx[3]));
    mt = fmaxf(mt, __shfl_xor(mt, 16));
    mt = fmaxf(mt, __shfl_xor(mt, 32));
    if (!__all(mt - mrun <= 8.f)) {  // defer-max (T13)
      float mnew = fmaxf(mrun, mt);
      float corr = exp2f(mrun - mnew);
      mrun = mnew;
      lrun *= corr;
      float cr[4];
#pragma unroll
      for (int r = 0; r < 4; ++r) cr[r] = __shfl(corr, kg * 4 + r);
#pragma unroll
      for (int n = 0; n < 4; ++n) {
        oacc[n][0] *= cr[0]; oacc[n][1] *= cr[1];
        oacc[n][2] *= cr[2]; oacc[n][3] *= cr[3];
      }
    }
    float p[4][4];
    float su[4];
#pragma unroll
    for (int n = 0; n < 4; ++n) {
      p[n][0] = exp2f(sac[n][0] - mrun); p[n][1] = exp2f(sac[n][1] - mrun);
      p[n][2] = exp2f(sac[n][2] - mrun); p[n][3] = exp2f(sac[n][3] - mrun);
      su[n] = (p[n][0] + p[n][1]) + (p[n][2] + p[n][3]);
    }
    float sum = (su[0] + su[1]) + (su[2] + su[3]);
    sum += __shfl_xor(sum, 16);
    sum += __shfl_xor(sum, 32);
    lrun += sum;
#pragma unroll
    for (int n = 0; n < 4; ++n) {
      ushort4 pk;
      pk.x = f2bfu(p[n][0]); pk.y = f2bfu(p[n][1]);
      pk.z = f2bfu(p[n][2]); pk.w = f2bfu(p[n][3]);
      *(ushort4*)(pwb + (((n * 32 + kg * 8)) ^ (int)rsw)) = pk;
    }
    LGKM0;

    bf16x8 pf[2], vf[2][4];
    DSRO(pf[0], adPr[0], 0);
    DSRO(pf[1], adPr[1], 0);
#pragma unroll
    for (int n = 0; n < 4; ++n) {
      DSRO(vf[0][n], adF[n][0] + bo, 8192);
      DSRO(vf[1][n], adF[n][1] + bo, 8192);
    }
    LGKM0; SCHED0;
#pragma unroll
    for (int n = 0; n < 4; ++n) {
      oacc[n] = __builtin_amdgcn_mfma_f32_16x16x32_bf16(pf[0], vf[0][n], oacc[n], 0, 0, 0);
      oacc[n] = __builtin_amdgcn_mfma_f32_16x16x32_bf16(pf[1], vf[1][n], oacc[n], 0, 0, 0);
    }
    if (t < 15) {
      VM0;
      __syncthreads();
    }
  }

  float inv = 1.f / lrun;
  float ivr[4];
#pragma unroll
  for (int r = 0; r < 4; ++r) ivr[r] = __shfl(inv, kg * 4 + r);
#pragma unroll
  for (int r = 0; r < 4; ++r) {
    int s = q0 + kg * 4 + r;
    size_t base = ((size_t)(bb * 1024 + s)) * 1024 + hh * 64;
#pragma unroll
    for (int n = 0; n < 4; ++n)
      Ob[base + n * 16 + ri] = __float2bfloat16(oacc[n][r] * ivr[r]);
  }
#undef ASTAGE
}

// ---------------- fused residual + LayerNorm (2 or 3 inputs) ----------------
__global__ __launch_bounds__(256) void ln_kernel(
    const float* __restrict__ a, const float* __restrict__ b,
    const float* __restrict__ c,
    const float* __restrict__ gamma, const float* __restrict__ beta,
    float* __restrict__ out_f32, bf16* __restrict__ out_bf16) {
  int row = blockIdx.x;
  int tid = threadIdx.x;
  float4 av = ((const float4*)(a + (size_t)row * 1024))[tid];
  float4 bv = ((const float4*)(b + (size_t)row * 1024))[tid];
  float4 z;
  z.x = av.x + bv.x; z.y = av.y + bv.y; z.z = av.z + bv.z; z.w = av.w + bv.w;
  if (c) {
    float4 cv = ((const float4*)(c + (size_t)row * 1024))[tid];
    z.x += cv.x; z.y += cv.y; z.z += cv.z; z.w += cv.w;
  }
  float s = z.x + z.y + z.z + z.w;
  float ss = z.x * z.x + z.y * z.y + z.z * z.z + z.w * z.w;
#pragma unroll
  for (int o = 32; o >= 1; o >>= 1) { s += __shfl_xor(s, o); ss += __shfl_xor(ss, o); }
  __shared__ float red[8];
  int wid = tid >> 6;
  if ((tid & 63) == 0) { red[wid] = s; red[4 + wid] = ss; }
  __syncthreads();
  s = red[0] + red[1] + red[2] + red[3];
  ss = red[4] + red[5] + red[6] + red[7];
  float mean = s * (1.f / 1024.f);
  float var = ss * (1.f / 1024.f) - mean * mean;
  var = var > 0.f ? var : 0.f;
  float inv = 1.f / (sqrtf(var) + EPS_LN);
  float4 g = ((const float4*)gamma)[tid];
  float4 be = ((const float4*)beta)[tid];
  float4 y;
  y.x = (z.x - mean) * inv * g.x + be.x;
  y.y = (z.y - mean) * inv * g.y + be.y;
  y.z = (z.z - mean) * inv * g.z + be.z;
  y.w = (z.w - mean) * inv * g.w + be.w;
  ((float4*)(out_f32 + (size_t)row * 1024))[tid] = y;
  if (out_bf16) {
    ushort4 o;
    o.x = f2bfu(y.x); o.y = f2bfu(y.y); o.z = f2bfu(y.z); o.w = f2bfu(y.w);
    ((ushort4*)(out_bf16 + (size_t)row * 1024))[tid] = o;
  }
}

// ---------------- launch ----------------
extern "C" void kernel_launch(void* const* d_in, const int* in_sizes, int n_in,
                              void* d_out, int out_size, void* d_ws, size_t ws_size,
                              hipStream_t stream) {
  const float* x = (const float*)d_in[0];
  const float* wq = (const float*)d_in[1];
  const float* bq = (const float*)d_in[2];
  const float* wk = (const float*)d_in[3];
  const float* bk = (const float*)d_in[4];
  const float* wv = (const float*)d_in[5];
  const float* bv = (const float*)d_in[6];
  const float* wo_w = (const float*)d_in[7];
  const float* wo_b = (const float*)d_in[8];
  const float* g1 = (const float*)d_in[9];
  const float* b1 = (const float*)d_in[10];
  const float* ff1w = (const float*)d_in[11];
  const float* ff1b = (const float*)d_in[12];
  const float* ff2w = (const float*)d_in[13];
  const float* ff2b = (const float*)d_in[14];
  const float* g2 = (const float*)d_in[15];
  const float* b2 = (const float*)d_in[16];

  char* ws = (char*)d_ws;
  size_t off = 0;
  auto alloc = [&](size_t bytes) {
    char* p = ws + off;
    off += (bytes + 255) & ~(size_t)255;
    return p;
  };
  bf16* xb = (bf16*)alloc((size_t)NTOK * 1024 * 2);
  bf16* wqkvt = (bf16*)alloc((size_t)3072 * 1024 * 2);
  bf16* wot = (bf16*)alloc((size_t)1024 * 1024 * 2);
  bf16* ff1t = (bf16*)alloc((size_t)2048 * 1024 * 2);
  bf16* ff2t = (bf16*)alloc((size_t)1024 * 2048 * 2);
  float* qkvbias = (float*)alloc(3072 * 4);
  bf16* qbuf = (bf16*)alloc((size_t)64 * 1024 * 64 * 2);
  bf16* kbuf = (bf16*)alloc((size_t)64 * 1024 * 64 * 2);
  bf16* vbuf = (bf16*)alloc((size_t)64 * 1024 * 64 * 2);
  bf16* vtb = (bf16*)alloc((size_t)64 * 64 * 1024 * 2);
  bf16* attnb = (bf16*)alloc((size_t)NTOK * 1024 * 2);
  float* proj = (float*)alloc((size_t)2 * NTOK * 1024 * 4);  // 2 split-K partials
  bf16* hb = (bf16*)alloc((size_t)NTOK * 1024 * 2);
  bf16* ff1o = qbuf;            // reuse q+k region (dead after attention)
  float* hbuf = (float*)d_out;  // f32 h scratch (fully rewritten by LN2)

  // prep
  cvt_bf16_kernel<<<(NTOK * 1024 / 4 + 255) / 256, 256, 0, stream>>>(x, xb, NTOK * 1024 / 4);
  transpose_cvt<float><<<dim3(2, 32, 16), 256, 0, stream>>>(wq, wqkvt, 1024, 64);
  transpose_cvt<float><<<dim3(2, 32, 16), 256, 0, stream>>>(wk, wqkvt + 1024 * 1024, 1024, 64);
  transpose_cvt<float><<<dim3(2, 32, 16), 256, 0, stream>>>(wv, wqkvt + 2 * 1024 * 1024, 1024, 64);
  transpose_cvt<float><<<dim3(32, 32, 1), 256, 0, stream>>>(wo_w, wot, 1024, 1024);
  transpose_cvt<float><<<dim3(64, 32, 1), 256, 0, stream>>>(ff1w, ff1t, 1024, 2048);
  transpose_cvt<float><<<dim3(32, 64, 1), 256, 0, stream>>>(ff2w, ff2t, 2048, 1024);
  pack_bias_kernel<<<12, 256, 0, stream>>>(bq, bk, bv, qkvbias);

  // QKV: [4096,1024] x [3072,1024]^T, 192 blocks; Q pre-scaled by 0.125*log2e
  gemm256<<<192, 512, 0, stream>>>(xb, 1024, wqkvt, 1024, 4096, 3072, 1024,
                                   16, 12, 1, qkvbias,
                                   nullptr, nullptr, qbuf, kbuf, vbuf, EPI_QKV);
  // V -> V^T per (b,h) (natural key order)
  transpose_cvt<bf16><<<dim3(2, 32, 64), 256, 0, stream>>>(vbuf, vtb, 1024, 64);
  // attention: 1024 blocks x 4 waves, swapped-QK lane-local softmax
  attn_kernel<<<dim3(1024), 256, 0, stream>>>(qbuf, kbuf, vtb, attnb);
  // output projection, split-K=2 (partials) -> proj[0], proj[1]
  gemm256<<<128, 512, 0, stream>>>(attnb, 1024, wot, 1024, 4096, 1024, 512,
                                   16, 4, 2, wo_b,
                                   proj, nullptr, nullptr, nullptr, nullptr, EPI_F32);
  // LN1: h = LN(x + projA + projB)
  ln_kernel<<<4096, 256, 0, stream>>>(x, proj, proj + (size_t)NTOK * 1024,
                                      g1, b1, hbuf, hb);
  // FF1 + ReLU: [4096,1024] x [2048,1024]^T, 128 blocks
  gemm256<<<128, 512, 0, stream>>>(hb, 1024, ff1t, 1024, 4096, 2048, 1024,
                                   16, 8, 1, ff1b,
                                   nullptr, ff1o, nullptr, nullptr, nullptr, EPI_RELU_BF16);
  // FF2: [4096,2048] x [1024,2048]^T, split-K=2 -> proj partials (reused)
  gemm256<<<128, 512, 0, stream>>>(ff1o, 2048, ff2t, 2048, 4096, 1024, 1024,
                                   16, 4, 2, ff2b,
                                   proj, nullptr, nullptr, nullptr, nullptr, EPI_F32);
  // LN2 -> d_out
  ln_kernel<<<4096, 256, 0, stream>>>(hbuf, proj, proj + (size_t)NTOK * 1024,
                                      g2, b2, (float*)d_out, nullptr);
}

// Round 9
// 176.799 us; speedup vs baseline: 1.2685x; 1.2685x over previous
//
#include <hip/hip_runtime.h>
#include <hip/hip_bf16.h>

typedef __attribute__((ext_vector_type(8))) short bf16x8;
typedef __attribute__((ext_vector_type(4))) float f32x4;
using bf16 = __hip_bfloat16;

#define NTOK 4096
#define EPS_LN 1e-5f
#define QSCL 0.1803368801111244f  // 0.125 * log2(e): softmax in exp2 domain

enum { EPI_F32 = 0, EPI_QKV = 1, EPI_RELU_BF16 = 2 };

#define VM8 asm volatile("s_waitcnt vmcnt(8)" ::: "memory")
#define VM0 asm volatile("s_waitcnt vmcnt(0)" ::: "memory")
#define LGKM0 asm volatile("s_waitcnt lgkmcnt(0)" ::: "memory")
#define SCHED0 __builtin_amdgcn_sched_barrier(0)
#define NOVM
#define DSRO(dst, ad, off) \
  asm volatile("ds_read_b128 %0, %1 offset:" #off : "=v"(dst) : "v"(ad))

__device__ inline void gload_lds16(const void* g, void* l) {
  __builtin_amdgcn_global_load_lds(
      (const __attribute__((address_space(1))) char*)g,
      (__attribute__((address_space(3))) char*)l, 16, 0, 0);
}

__device__ inline unsigned ldsoff(const void* p) {
  return (unsigned)(size_t)(const __attribute__((address_space(3))) char*)p;
}

__device__ inline unsigned short f2bfu(float x) {
  bf16 h = __float2bfloat16(x);
  return __builtin_bit_cast(unsigned short, h);
}
__device__ inline bf16 to_bf16(float v) { return __float2bfloat16(v); }
__device__ inline bf16 to_bf16(bf16 v) { return v; }

// ---------------- prep kernels ----------------

__global__ __launch_bounds__(256) void cvt_bf16_kernel(const float* __restrict__ src,
                                                       bf16* __restrict__ dst, int n4) {
  int i = blockIdx.x * 256 + threadIdx.x;
  if (i >= n4) return;
  float4 v = ((const float4*)src)[i];
  ushort4 o;
  o.x = f2bfu(v.x); o.y = f2bfu(v.y); o.z = f2bfu(v.z); o.w = f2bfu(v.w);
  ((ushort4*)dst)[i] = o;
}

template <typename ST>
__global__ __launch_bounds__(256) void transpose_cvt(const ST* __restrict__ src,
                                                     bf16* __restrict__ dst, int R, int C) {
  __shared__ bf16 tile[32][33];
  int o = blockIdx.z;
  int r0 = blockIdx.y * 32, c0 = blockIdx.x * 32;
  int tx = threadIdx.x & 31, ty = threadIdx.x >> 5;
  const ST* s = src + (size_t)o * R * C;
  bf16* d = dst + (size_t)o * R * C;
#pragma unroll
  for (int i = 0; i < 32; i += 8)
    tile[ty + i][tx] = to_bf16(s[(size_t)(r0 + ty + i) * C + (c0 + tx)]);
  __syncthreads();
#pragma unroll
  for (int i = 0; i < 32; i += 8)
    d[(size_t)(c0 + ty + i) * R + (r0 + tx)] = tile[tx][ty + i];
}

__global__ __launch_bounds__(256) void pack_bias_kernel(const float* __restrict__ bq,
                                                        const float* __restrict__ bk,
                                                        const float* __restrict__ bv,
                                                        float* __restrict__ out) {
  int i = blockIdx.x * 256 + threadIdx.x;
  if (i >= 3072) return;
  out[i] = (i < 1024) ? bq[i] : (i < 2048 ? bk[i - 1024] : bv[i - 2048]);
}

// ---------------- GEMM: 128x128 tile, dbuf, 4 waves, 2 blocks/CU ----------
// C[M,N] = A[M,K] x Bt[N,K]^T. 256 thr = 4 waves (2m x 2n), per-wave 64x64.
// LDS 64KB -> 2 blocks/CU: cross-block wave overlap hides stage latency.
// Stage tile t+2 during tile t; vmcnt(8) per tile (1-tile cover).

// stage one 32KB K-tile (A 16KB + B 16KB): 8 gload_lds per thread
#define STG(KOFF, DD) { _Pragma("unroll") for (int q = 0; q < 4; ++q) { \
    gload_lds16(gA0 + (KOFF) + (size_t)(q * 32) * lda2, \
                sAb + (DD) * 16384 + q * 4096 + w * 1024); \
    gload_lds16(gB0 + (KOFF) + (size_t)(q * 32) * ldb2, \
                sBb + (DD) * 16384 + q * 4096 + w * 1024); } }

#define TILE(OFFLIT, STG_, VMS) { \
  _Pragma("unroll") for (int i = 0; i < 4; ++i) { \
    DSRO(a[i][0], adA[i][0], OFFLIT); \
    DSRO(a[i][1], adA[i][1], OFFLIT); \
  } \
  _Pragma("unroll") for (int j = 0; j < 4; ++j) { \
    DSRO(b[j][0], adB[j][0], OFFLIT); \
    DSRO(b[j][1], adB[j][1], OFFLIT); \
  } \
  LGKM0; SCHED0; \
  __builtin_amdgcn_s_barrier(); \
  STG_; \
  __builtin_amdgcn_s_setprio(1); \
  _Pragma("unroll") for (int i = 0; i < 4; ++i) \
  _Pragma("unroll") for (int j = 0; j < 4; ++j) \
  _Pragma("unroll") for (int kk = 0; kk < 2; ++kk) \
    acc[i][j] = __builtin_amdgcn_mfma_f32_16x16x32_bf16( \
        a[i][kk], b[j][kk], acc[i][j], 0, 0, 0); \
  __builtin_amdgcn_s_setprio(0); \
  VMS; \
  __builtin_amdgcn_s_barrier(); }

__global__ __launch_bounds__(256, 2) void gemm128(
    const bf16* __restrict__ A, int lda,
    const bf16* __restrict__ Bt, int ldb,
    int M, int N, int K,  // K % 128 == 0
    int nbm, int nbn,
    const float* __restrict__ bias,
    float* __restrict__ Cf, bf16* __restrict__ Cb,
    bf16* __restrict__ Qd, bf16* __restrict__ Kd, bf16* __restrict__ Vd,
    int mode) {
  __shared__ bf16 sA[2][128][64];
  __shared__ bf16 sB[2][128][64];
  const int nwg = nbm * nbn;
  const int orig = blockIdx.x;
  const int wgid = (orig % 8) * (nwg / 8) + orig / 8;  // nwg % 8 == 0
  const int bm = wgid / nbn, bn = wgid % nbn;
  const int tid = threadIdx.x;
  const int w = tid >> 6, lane = tid & 63;
  const int wm = w >> 1, wn = w & 1;
  const int ri = lane & 15, kg = lane >> 4;
  const bf16* Ab = A + (size_t)bm * 128 * lda;
  const bf16* Bb = Bt + (size_t)bn * 128 * ldb;
  const int NT = K / 64;
  const size_t lda2 = (size_t)lda * 2, ldb2 = (size_t)ldb * 2;
  char* sAb = (char*)&sA[0][0][0];
  char* sBb = (char*)&sB[0][0][0];

  // loop-invariant LDS read addresses (128B rows, swz = (row&7)<<4)
  unsigned adA[4][2], adB[4][2];
  const unsigned sA0 = ldsoff(sAb), sB0 = ldsoff(sBb);
#pragma unroll
  for (int i = 0; i < 4; ++i) {
    int row = wm * 64 + i * 16 + ri;
    unsigned swz = (unsigned)((row & 7) << 4);
    adA[i][0] = sA0 + row * 128 + ((kg * 16) ^ swz);
    adA[i][1] = sA0 + row * 128 + ((64 + kg * 16) ^ swz);
  }
#pragma unroll
  for (int j = 0; j < 4; ++j) {
    int row = wn * 64 + j * 16 + ri;
    unsigned swz = (unsigned)((row & 7) << 4);
    adB[j][0] = sB0 + row * 128 + ((kg * 16) ^ swz);
    adB[j][1] = sB0 + row * 128 + ((64 + kg * 16) ^ swz);
  }

  // per-lane stage base (row = tid>>3, pre-swizzled col), +256B per tile-pair
  const int r0 = tid >> 3;
  const int cb0 = ((tid & 7) * 16) ^ ((r0 & 7) << 4);
  const char* gA0 = (const char*)Ab + (size_t)r0 * lda2 + cb0;
  const char* gB0 = (const char*)Bb + (size_t)r0 * ldb2 + cb0;

  f32x4 acc[4][4] = {};
  bf16x8 a[4][2], b[4][2];

  // prologue: tiles 0,1 -> bufs 0,1
  STG(0, 0) STG(128, 1)
  VM8;  // tile 0 landed
  __builtin_amdgcn_s_barrier();

  const int niter = NT / 2 - 1;
  for (int it = 0; it < niter; ++it) {
    TILE(0,     STG(256, 0), VM8)   // tile 2it   (buf0); stage 2it+2
    TILE(16384, STG(384, 1), VM8)   // tile 2it+1 (buf1); stage 2it+3
    gA0 += 256; gB0 += 256;
  }
  // tail: tiles NT-2 (buf0), NT-1 (buf1); no staging
  TILE(0,     , VM0)
  TILE(16384, , NOVM)

  // epilogue: line-contiguous writes (nf innermost)
  const int colbase = bn * 128 + wn * 64 + ri;
  float bv4[4];
#pragma unroll
  for (int nf = 0; nf < 4; ++nf)
    bv4[nf] = bias ? bias[colbase + nf * 16] : 0.f;

  if (mode == EPI_QKV) {
    int col0 = bn * 128 + wn * 64;  // which/hh wave-uniform (64 | 1024)
    int which = col0 >> 10, hh = (col0 >> 6) & 15;
    bf16* dst = (which == 0) ? Qd : (which == 1) ? Kd : Vd;
    float scl = (which == 0) ? QSCL : 1.0f;  // fold softmax scale+log2e into Q
#pragma unroll
    for (int mf = 0; mf < 4; ++mf)
#pragma unroll
      for (int r = 0; r < 4; ++r) {
        int row = bm * 128 + wm * 64 + mf * 16 + kg * 4 + r;
        int b2 = row >> 10, s = row & 1023;
        bf16* o = dst + (((size_t)(b2 * 16 + hh)) * 1024 + s) * 64;
#pragma unroll
        for (int nf = 0; nf < 4; ++nf)
          o[nf * 16 + ri] = __float2bfloat16((acc[mf][nf][r] + bv4[nf]) * scl);
      }
  } else if (mode == EPI_F32) {
#pragma unroll
    for (int mf = 0; mf < 4; ++mf)
#pragma unroll
      for (int r = 0; r < 4; ++r) {
        int row = bm * 128 + wm * 64 + mf * 16 + kg * 4 + r;
        float* o = Cf + (size_t)row * N + colbase;
#pragma unroll
        for (int nf = 0; nf < 4; ++nf) o[nf * 16] = acc[mf][nf][r] + bv4[nf];
      }
  } else {  // EPI_RELU_BF16
#pragma unroll
    for (int mf = 0; mf < 4; ++mf)
#pragma unroll
      for (int r = 0; r < 4; ++r) {
        int row = bm * 128 + wm * 64 + mf * 16 + kg * 4 + r;
        bf16* o = Cb + (size_t)row * N + colbase;
#pragma unroll
        for (int nf = 0; nf < 4; ++nf) {
          float v = acc[mf][nf][r] + bv4[nf];
          o[nf * 16] = __float2bfloat16(v > 0.f ? v : 0.f);
        }
      }
  }
}

// ---------------- flash attention: swapped-QK, lane-local softmax ----------------
// grid 1024 = 64 bh * 16 q-tiles (XCD-grouped). 4 waves x 16 q-rows; 4 blk/CU.
__global__ __launch_bounds__(256, 4) void attn_kernel(
    const bf16* __restrict__ Qb, const bf16* __restrict__ Kb,
    const bf16* __restrict__ Vs, bf16* __restrict__ Ob) {
  __shared__ bf16 KV[2][2][64][64];  // [dbuf][0=K rows=key | 1=V^T rows=d]
  __shared__ bf16 Ps[4][16][64];     // per-wave P [query][key], swizzled
  const int orig = blockIdx.x;
  const int blk = (orig & 7) * 128 + (orig >> 3);  // 1024 % 8 == 0
  const int bh = blk >> 4, qt = blk & 15;
  const int bb = bh >> 4, hh = bh & 15;
  const int tid = threadIdx.x, w = tid >> 6, lane = tid & 63;
  const int ri = lane & 15, kg = lane >> 4, r8 = lane >> 3;
  const int cb = ((lane & 7) * 16) ^ ((r8 & 7) << 4);  // pre-swizzled source
  const unsigned rsw = (unsigned)((ri & 7) << 4);
  const bf16* qp = Qb + (size_t)bh * 65536;
  const bf16* kp = Kb + (size_t)bh * 65536;
  const bf16* vp = Vs + (size_t)bh * 65536;
  const int q0 = qt * 64 + w * 16;
  const int c0 = w * 2, c1 = c0 + 1;

  unsigned offk0 = (unsigned)((kg * 16) ^ (int)rsw);
  unsigned offk1 = (unsigned)((64 + kg * 16) ^ (int)rsw);
  unsigned adF[4][2];
  const unsigned kv0 = ldsoff(&KV[0][0][0][0]);
#pragma unroll
  for (int n = 0; n < 4; ++n) {
    unsigned row = (unsigned)((n * 16 + ri) * 128);
    adF[n][0] = kv0 + row + offk0;
    adF[n][1] = kv0 + row + offk1;
  }
  const unsigned ps0 = ldsoff(&Ps[0][0][0]) + (unsigned)(w * 2048 + ri * 128);
  unsigned adPr[2] = {ps0 + offk0, ps0 + offk1};
  char* pwb = (char*)&Ps[0][0][0] + w * 2048 + ri * 128;

  bf16x8 qf[2];
  qf[0] = *(const bf16x8*)(qp + (size_t)(q0 + ri) * 64 + kg * 8);
  qf[1] = *(const bf16x8*)(qp + (size_t)(q0 + ri) * 64 + 32 + kg * 8);

  f32x4 oacc[4] = {};
  float mrun = -1e30f, lrun = 0.f;

#define ASTAGE(T, D) { \
    gload_lds16((const char*)(kp + (size_t)((T) * 64 + c0 * 8 + r8) * 64) + cb, \
                (char*)KV + (D) * 16384 + c0 * 1024); \
    gload_lds16((const char*)(kp + (size_t)((T) * 64 + c1 * 8 + r8) * 64) + cb, \
                (char*)KV + (D) * 16384 + c1 * 1024); \
    gload_lds16((const char*)(vp + (size_t)(c0 * 8 + r8) * 1024 + (T) * 64) + cb, \
                (char*)KV + (D) * 16384 + 8192 + c0 * 1024); \
    gload_lds16((const char*)(vp + (size_t)(c1 * 8 + r8) * 1024 + (T) * 64) + cb, \
                (char*)KV + (D) * 16384 + 8192 + c1 * 1024); }

  ASTAGE(0, 0);
  VM0;
  __syncthreads();

  for (int t = 0; t < 16; ++t) {
    const int cur = t & 1;
    if (t < 15) ASTAGE(t + 1, cur ^ 1);  // flies across the whole tile
    const unsigned bo = (unsigned)(cur * 16384);

    bf16x8 kf[2][4];
#pragma unroll
    for (int n = 0; n < 4; ++n) {
      DSRO(kf[0][n], adF[n][0] + bo, 0);
      DSRO(kf[1][n], adF[n][1] + bo, 0);
    }
    LGKM0; SCHED0;
    f32x4 sac[4] = {};
#pragma unroll
    for (int n = 0; n < 4; ++n) {
      sac[n] = __builtin_amdgcn_mfma_f32_16x16x32_bf16(kf[0][n], qf[0], sac[n], 0, 0, 0);
      sac[n] = __builtin_amdgcn_mfma_f32_16x16x32_bf16(kf[1][n], qf[1], sac[n], 0, 0, 0);
    }

    float mx[4];
#pragma unroll
    for (int n = 0; n < 4; ++n)
      mx[n] = fmaxf(fmaxf(sac[n][0], sac[n][1]), fmaxf(sac[n][2], sac[n][3]));
    float mt = fmaxf(fmaxf(mx[0], mx[1]), fmaxf(mx[2], mx[3]));
    mt = fmaxf(mt, __shfl_xor(mt, 16));
    mt = fmaxf(mt, __shfl_xor(mt, 32));
    if (!__all(mt - mrun <= 8.f)) {  // defer-max (T13)
      float mnew = fmaxf(mrun, mt);
      float corr = exp2f(mrun - mnew);
      mrun = mnew;
      lrun *= corr;
      float cr[4];
#pragma unroll
      for (int r = 0; r < 4; ++r) cr[r] = __shfl(corr, kg * 4 + r);
#pragma unroll
      for (int n = 0; n < 4; ++n) {
        oacc[n][0] *= cr[0]; oacc[n][1] *= cr[1];
        oacc[n][2] *= cr[2]; oacc[n][3] *= cr[3];
      }
    }
    float p[4][4];
    float su[4];
#pragma unroll
    for (int n = 0; n < 4; ++n) {
      p[n][0] = exp2f(sac[n][0] - mrun); p[n][1] = exp2f(sac[n][1] - mrun);
      p[n][2] = exp2f(sac[n][2] - mrun); p[n][3] = exp2f(sac[n][3] - mrun);
      su[n] = (p[n][0] + p[n][1]) + (p[n][2] + p[n][3]);
    }
    float sum = (su[0] + su[1]) + (su[2] + su[3]);
    sum += __shfl_xor(sum, 16);
    sum += __shfl_xor(sum, 32);
    lrun += sum;
#pragma unroll
    for (int n = 0; n < 4; ++n) {
      ushort4 pk;
      pk.x = f2bfu(p[n][0]); pk.y = f2bfu(p[n][1]);
      pk.z = f2bfu(p[n][2]); pk.w = f2bfu(p[n][3]);
      *(ushort4*)(pwb + (((n * 32 + kg * 8)) ^ (int)rsw)) = pk;
    }
    LGKM0;

    bf16x8 pf[2], vf[2][4];
    DSRO(pf[0], adPr[0], 0);
    DSRO(pf[1], adPr[1], 0);
#pragma unroll
    for (int n = 0; n < 4; ++n) {
      DSRO(vf[0][n], adF[n][0] + bo, 8192);
      DSRO(vf[1][n], adF[n][1] + bo, 8192);
    }
    LGKM0; SCHED0;
#pragma unroll
    for (int n = 0; n < 4; ++n) {
      oacc[n] = __builtin_amdgcn_mfma_f32_16x16x32_bf16(pf[0], vf[0][n], oacc[n], 0, 0, 0);
      oacc[n] = __builtin_amdgcn_mfma_f32_16x16x32_bf16(pf[1], vf[1][n], oacc[n], 0, 0, 0);
    }
    if (t < 15) {
      VM0;
      __syncthreads();
    }
  }

  float inv = 1.f / lrun;
  float ivr[4];
#pragma unroll
  for (int r = 0; r < 4; ++r) ivr[r] = __shfl(inv, kg * 4 + r);
#pragma unroll
  for (int r = 0; r < 4; ++r) {
    int s = q0 + kg * 4 + r;
    size_t base = ((size_t)(bb * 1024 + s)) * 1024 + hh * 64;
#pragma unroll
    for (int n = 0; n < 4; ++n)
      Ob[base + n * 16 + ri] = __float2bfloat16(oacc[n][r] * ivr[r]);
  }
#undef ASTAGE
}

// ---------------- fused residual + LayerNorm ----------------
__global__ __launch_bounds__(256) void ln_kernel(
    const float* __restrict__ a, const float* __restrict__ b,
    const float* __restrict__ gamma, const float* __restrict__ beta,
    float* __restrict__ out_f32, bf16* __restrict__ out_bf16) {
  int row = blockIdx.x;
  int tid = threadIdx.x;
  float4 av = ((const float4*)(a + (size_t)row * 1024))[tid];
  float4 bv = ((const float4*)(b + (size_t)row * 1024))[tid];
  float4 z;
  z.x = av.x + bv.x; z.y = av.y + bv.y; z.z = av.z + bv.z; z.w = av.w + bv.w;
  float s = z.x + z.y + z.z + z.w;
  float ss = z.x * z.x + z.y * z.y + z.z * z.z + z.w * z.w;
#pragma unroll
  for (int o = 32; o >= 1; o >>= 1) { s += __shfl_xor(s, o); ss += __shfl_xor(ss, o); }
  __shared__ float red[8];
  int wid = tid >> 6;
  if ((tid & 63) == 0) { red[wid] = s; red[4 + wid] = ss; }
  __syncthreads();
  s = red[0] + red[1] + red[2] + red[3];
  ss = red[4] + red[5] + red[6] + red[7];
  float mean = s * (1.f / 1024.f);
  float var = ss * (1.f / 1024.f) - mean * mean;
  var = var > 0.f ? var : 0.f;
  float inv = 1.f / (sqrtf(var) + EPS_LN);
  float4 g = ((const float4*)gamma)[tid];
  float4 be = ((const float4*)beta)[tid];
  float4 y;
  y.x = (z.x - mean) * inv * g.x + be.x;
  y.y = (z.y - mean) * inv * g.y + be.y;
  y.z = (z.z - mean) * inv * g.z + be.z;
  y.w = (z.w - mean) * inv * g.w + be.w;
  ((float4*)(out_f32 + (size_t)row * 1024))[tid] = y;
  if (out_bf16) {
    ushort4 o;
    o.x = f2bfu(y.x); o.y = f2bfu(y.y); o.z = f2bfu(y.z); o.w = f2bfu(y.w);
    ((ushort4*)(out_bf16 + (size_t)row * 1024))[tid] = o;
  }
}

// ---------------- launch ----------------
extern "C" void kernel_launch(void* const* d_in, const int* in_sizes, int n_in,
                              void* d_out, int out_size, void* d_ws, size_t ws_size,
                              hipStream_t stream) {
  const float* x = (const float*)d_in[0];
  const float* wq = (const float*)d_in[1];
  const float* bq = (const float*)d_in[2];
  const float* wk = (const float*)d_in[3];
  const float* bk = (const float*)d_in[4];
  const float* wv = (const float*)d_in[5];
  const float* bv = (const float*)d_in[6];
  const float* wo_w = (const float*)d_in[7];
  const float* wo_b = (const float*)d_in[8];
  const float* g1 = (const float*)d_in[9];
  const float* b1 = (const float*)d_in[10];
  const float* ff1w = (const float*)d_in[11];
  const float* ff1b = (const float*)d_in[12];
  const float* ff2w = (const float*)d_in[13];
  const float* ff2b = (const float*)d_in[14];
  const float* g2 = (const float*)d_in[15];
  const float* b2 = (const float*)d_in[16];

  char* ws = (char*)d_ws;
  size_t off = 0;
  auto alloc = [&](size_t bytes) {
    char* p = ws + off;
    off += (bytes + 255) & ~(size_t)255;
    return p;
  };
  bf16* xb = (bf16*)alloc((size_t)NTOK * 1024 * 2);
  bf16* wqkvt = (bf16*)alloc((size_t)3072 * 1024 * 2);
  bf16* wot = (bf16*)alloc((size_t)1024 * 1024 * 2);
  bf16* ff1t = (bf16*)alloc((size_t)2048 * 1024 * 2);
  bf16* ff2t = (bf16*)alloc((size_t)1024 * 2048 * 2);
  float* qkvbias = (float*)alloc(3072 * 4);
  bf16* qbuf = (bf16*)alloc((size_t)64 * 1024 * 64 * 2);
  bf16* kbuf = (bf16*)alloc((size_t)64 * 1024 * 64 * 2);
  bf16* vbuf = (bf16*)alloc((size_t)64 * 1024 * 64 * 2);
  bf16* vtb = (bf16*)alloc((size_t)64 * 64 * 1024 * 2);
  bf16* attnb = (bf16*)alloc((size_t)NTOK * 1024 * 2);
  float* proj = (float*)alloc((size_t)NTOK * 1024 * 4);
  bf16* hb = (bf16*)alloc((size_t)NTOK * 1024 * 2);
  bf16* ff1o = qbuf;            // reuse q+k region (dead after attention)
  float* hbuf = (float*)d_out;  // f32 h scratch (fully rewritten by LN2)

  // prep
  cvt_bf16_kernel<<<(NTOK * 1024 / 4 + 255) / 256, 256, 0, stream>>>(x, xb, NTOK * 1024 / 4);
  transpose_cvt<float><<<dim3(2, 32, 16), 256, 0, stream>>>(wq, wqkvt, 1024, 64);
  transpose_cvt<float><<<dim3(2, 32, 16), 256, 0, stream>>>(wk, wqkvt + 1024 * 1024, 1024, 64);
  transpose_cvt<float><<<dim3(2, 32, 16), 256, 0, stream>>>(wv, wqkvt + 2 * 1024 * 1024, 1024, 64);
  transpose_cvt<float><<<dim3(32, 32, 1), 256, 0, stream>>>(wo_w, wot, 1024, 1024);
  transpose_cvt<float><<<dim3(64, 32, 1), 256, 0, stream>>>(ff1w, ff1t, 1024, 2048);
  transpose_cvt<float><<<dim3(32, 64, 1), 256, 0, stream>>>(ff2w, ff2t, 2048, 1024);
  pack_bias_kernel<<<12, 256, 0, stream>>>(bq, bk, bv, qkvbias);

  // QKV: [4096,1024] x [3072,1024]^T, 768 blocks (3/CU)
  gemm128<<<768, 256, 0, stream>>>(xb, 1024, wqkvt, 1024, 4096, 3072, 1024,
                                   32, 24, qkvbias,
                                   nullptr, nullptr, qbuf, kbuf, vbuf, EPI_QKV);
  // V -> V^T per (b,h)
  transpose_cvt<bf16><<<dim3(2, 32, 64), 256, 0, stream>>>(vbuf, vtb, 1024, 64);
  // attention: 1024 blocks x 4 waves, swapped-QK lane-local softmax
  attn_kernel<<<dim3(1024), 256, 0, stream>>>(qbuf, kbuf, vtb, attnb);
  // output projection: 256 blocks
  gemm128<<<256, 256, 0, stream>>>(attnb, 1024, wot, 1024, 4096, 1024, 1024,
                                   32, 8, wo_b,
                                   proj, nullptr, nullptr, nullptr, nullptr, EPI_F32);
  // LN1: h = LN(x + proj)
  ln_kernel<<<4096, 256, 0, stream>>>(x, proj, g1, b1, hbuf, hb);
  // FF1 + ReLU: 512 blocks
  gemm128<<<512, 256, 0, stream>>>(hb, 1024, ff1t, 1024, 4096, 2048, 1024,
                                   32, 16, ff1b,
                                   nullptr, ff1o, nullptr, nullptr, nullptr, EPI_RELU_BF16);
  // FF2: 256 blocks, K=2048
  gemm128<<<256, 256, 0, stream>>>(ff1o, 2048, ff2t, 2048, 4096, 1024, 2048,
                                   32, 8, ff2b,
                                   proj, nullptr, nullptr, nullptr, nullptr, EPI_F32);
  // LN2 -> d_out
  ln_kernel<<<4096, 256, 0, stream>>>(hbuf, proj, g2, b2, (float*)d_out, nullptr);
}